// Round 1
// baseline (738.841 us; speedup 1.0000x reference)
//
#include <hip/hip_runtime.h>
#include <hip/hip_bf16.h>
#include <cstdint>
#include <cstddef>

#define N_NODES 50000
#define N_EDGES 800000
#define IN_DIM 256
#define HC 128          // HEADS*OUT_DIM
#define HEADS 4
#define NEG_SLOPE 0.2f
#define LN_EPS 1e-5f

__device__ __forceinline__ float lrelu(float x) { return x > 0.f ? x : NEG_SLOPE * x; }
// order-preserving float->uint encoding so atomicMax(u32) == float max
__device__ __forceinline__ unsigned enc_f(float f) {
    unsigned u = __float_as_uint(f);
    return (u & 0x80000000u) ? ~u : (u | 0x80000000u);
}
__device__ __forceinline__ float dec_f(unsigned u) {
    return __uint_as_float((u & 0x80000000u) ? (u & 0x7fffffffu) : ~u);
}

// K1: h = x@W (8 rows/block), fused a_s/a_d reduction + emax init with self-loop logit
__global__ __launch_bounds__(256) void k1_gemm(
    const float* __restrict__ x, const float* __restrict__ W,
    const float* __restrict__ att_src, const float* __restrict__ att_dst,
    float* __restrict__ h, float* __restrict__ a_s, float* __restrict__ a_d,
    unsigned* __restrict__ emax_enc)
{
    __shared__ float xs[8][IN_DIM];
    const int tid = threadIdx.x;
    const int n0 = blockIdx.x * 8;

    // stage 8 rows of x into LDS (512 float4, 2 per thread, coalesced)
    const float4* xg = (const float4*)(x + (size_t)n0 * IN_DIM);
    float4* xs4 = (float4*)&xs[0][0];
    xs4[tid] = xg[tid];
    xs4[tid + 256] = xg[tid + 256];
    __syncthreads();

    const int c = tid & 127;   // output column 0..127
    const int rg = tid >> 7;   // row group: rows rg*4 .. rg*4+3
    float acc0 = 0.f, acc1 = 0.f, acc2 = 0.f, acc3 = 0.f;
    const float* r0 = xs[rg * 4 + 0];
    const float* r1 = xs[rg * 4 + 1];
    const float* r2 = xs[rg * 4 + 2];
    const float* r3 = xs[rg * 4 + 3];
#pragma unroll 4
    for (int k = 0; k < IN_DIM; ++k) {
        float w = W[k * HC + c];        // coalesced, L2-resident (128 KB)
        acc0 += r0[k] * w;              // LDS broadcast reads (free)
        acc1 += r1[k] * w;
        acc2 += r2[k] * w;
        acc3 += r3[k] * w;
    }
    size_t hb = (size_t)(n0 + rg * 4) * HC + c;
    h[hb + 0 * HC] = acc0;
    h[hb + 1 * HC] = acc1;
    h[hb + 2 * HC] = acc2;
    h[hb + 3 * HC] = acc3;

    // per-(row,head) dot with att vectors via 32-lane butterfly (head = c>>5)
    float avs = att_src[c], avd = att_dst[c];
    float s0 = acc0 * avs, s1 = acc1 * avs, s2 = acc2 * avs, s3 = acc3 * avs;
    float d0 = acc0 * avd, d1 = acc1 * avd, d2 = acc2 * avd, d3 = acc3 * avd;
#pragma unroll
    for (int off = 16; off; off >>= 1) {
        s0 += __shfl_xor(s0, off, 32); d0 += __shfl_xor(d0, off, 32);
        s1 += __shfl_xor(s1, off, 32); d1 += __shfl_xor(d1, off, 32);
        s2 += __shfl_xor(s2, off, 32); d2 += __shfl_xor(d2, off, 32);
        s3 += __shfl_xor(s3, off, 32); d3 += __shfl_xor(d3, off, 32);
    }
    if ((c & 31) == 0) {
        int head = c >> 5;
        int n = n0 + rg * 4;
        float ss[4] = {s0, s1, s2, s3};
        float dd[4] = {d0, d1, d2, d3};
#pragma unroll
        for (int i = 0; i < 4; ++i) {
            int idx = (n + i) * HEADS + head;
            a_s[idx] = ss[i];
            a_d[idx] = dd[i];
            emax_enc[idx] = enc_f(lrelu(ss[i] + dd[i]));  // self-loop seeds the max
        }
    }
}

// K2: per-edge atomicMax of encoded logits into emax[dst]
__global__ __launch_bounds__(256) void k2_edge_max(
    const int* __restrict__ ei, const float* __restrict__ a_s,
    const float* __restrict__ a_d, unsigned* __restrict__ emax_enc)
{
    int e = blockIdx.x * 256 + threadIdx.x;
    if (e >= N_EDGES) return;
    int src = ei[e], dst = ei[N_EDGES + e];
    float4 s4 = *(const float4*)(a_s + (size_t)src * HEADS);
    float4 d4 = *(const float4*)(a_d + (size_t)dst * HEADS);
    unsigned* base = emax_enc + (size_t)dst * HEADS;
    atomicMax(base + 0, enc_f(lrelu(s4.x + d4.x)));
    atomicMax(base + 1, enc_f(lrelu(s4.y + d4.y)));
    atomicMax(base + 2, enc_f(lrelu(s4.z + d4.z)));
    atomicMax(base + 3, enc_f(lrelu(s4.w + d4.w)));
}

// K3: decode emax, seed denom/out_accum with self-loop term (also inits poisoned ws)
__global__ __launch_bounds__(256) void k3_node_init(
    const float* __restrict__ h, const float* __restrict__ a_s,
    const float* __restrict__ a_d, const unsigned* __restrict__ emax_enc,
    float* __restrict__ emaxf, float* __restrict__ denom, float* __restrict__ out_accum)
{
    int idx = blockIdx.x * 256 + threadIdx.x;   // [0, N_NODES*128)
    int n = idx >> 7, c = idx & 127, hd = c >> 5;
    int ih = n * HEADS + hd;
    float em = dec_f(emax_enc[ih]);
    float w = __expf(lrelu(a_s[ih] + a_d[ih]) - em);
    out_accum[idx] = h[idx] * w;
    if (c < HEADS) {
        int ih2 = n * HEADS + c;
        float em2 = dec_f(emax_enc[ih2]);
        emaxf[ih2] = em2;
        denom[ih2] = __expf(lrelu(a_s[ih2] + a_d[ih2]) - em2);
    }
}

// K4: one wave per edge — gather h[src], scale by unnormalized softmax weight,
// atomicAdd into out_accum[dst]; lane 0/32 add the weights into denom.
__global__ __launch_bounds__(256) void k4_edge_msg(
    const int* __restrict__ ei, const float* __restrict__ a_s,
    const float* __restrict__ a_d, const float* __restrict__ emaxf,
    const float* __restrict__ h, float* __restrict__ denom,
    float* __restrict__ out_accum)
{
    int gid = blockIdx.x * 256 + threadIdx.x;
    int e = gid >> 6;
    int lane = gid & 63;
    if (e >= N_EDGES) return;
    int src = ei[e], dst = ei[N_EDGES + e];
    int hd0 = lane >> 5, hd1 = 2 + hd0;
    int db4 = dst * HEADS;
    int sb4 = src * HEADS;
    float w0 = __expf(lrelu(a_s[sb4 + hd0] + a_d[db4 + hd0]) - emaxf[db4 + hd0]);
    float w1 = __expf(lrelu(a_s[sb4 + hd1] + a_d[db4 + hd1]) - emaxf[db4 + hd1]);
    size_t sb = (size_t)src * HC, db = (size_t)dst * HC;
    atomicAdd(out_accum + db + lane,      h[sb + lane]      * w0);
    atomicAdd(out_accum + db + lane + 64, h[sb + lane + 64] * w1);
    if ((lane & 31) == 0) {
        atomicAdd(denom + db4 + hd0, w0);
        atomicAdd(denom + db4 + hd1, w1);
    }
}

// K5: wave per node — normalize, +bias, LayerNorm (shuffle reduce), ELU, store
__global__ __launch_bounds__(256) void k5_final(
    const float* __restrict__ out_accum, const float* __restrict__ denom,
    const float* __restrict__ bias, const float* __restrict__ gamma,
    const float* __restrict__ beta, float* __restrict__ out)
{
    int gid = blockIdx.x * 256 + threadIdx.x;
    int n = gid >> 6, lane = gid & 63;
    if (n >= N_NODES) return;
    size_t base = (size_t)n * HC;
    int c0 = lane, c1 = lane + 64;
    float v0 = out_accum[base + c0] / denom[n * HEADS + (c0 >> 5)] + bias[c0];
    float v1 = out_accum[base + c1] / denom[n * HEADS + (c1 >> 5)] + bias[c1];
    float s = v0 + v1;
#pragma unroll
    for (int off = 32; off; off >>= 1) s += __shfl_xor(s, off, 64);
    float mu = s * (1.f / 128.f);
    float d0 = v0 - mu, d1 = v1 - mu;
    float q = d0 * d0 + d1 * d1;
#pragma unroll
    for (int off = 32; off; off >>= 1) q += __shfl_xor(q, off, 64);
    float rs = rsqrtf(q * (1.f / 128.f) + LN_EPS);
    float o0 = d0 * rs * gamma[c0] + beta[c0];
    float o1 = d1 * rs * gamma[c1] + beta[c1];
    o0 = o0 > 0.f ? o0 : __expf(o0) - 1.f;
    o1 = o1 > 0.f ? o1 : __expf(o1) - 1.f;
    out[base + c0] = o0;
    out[base + c1] = o1;
}

extern "C" void kernel_launch(void* const* d_in, const int* in_sizes, int n_in,
                              void* d_out, int out_size, void* d_ws, size_t ws_size,
                              hipStream_t stream) {
    const float* x       = (const float*)d_in[0];
    const int*   ei      = (const int*)d_in[1];   // [2, E] int32: row0=src, row1=dst
    const float* W       = (const float*)d_in[2];
    const float* att_src = (const float*)d_in[3];
    const float* att_dst = (const float*)d_in[4];
    const float* bias    = (const float*)d_in[5];
    const float* gamma   = (const float*)d_in[6];
    const float* beta    = (const float*)d_in[7];
    float* out = (float*)d_out;

    char* ws = (char*)d_ws;
    // layout (all 16B-aligned): h 25.6MB | out_accum 25.6MB | a_s .8MB | a_d .8MB
    //                           | emax_enc .8MB | emaxf .8MB | denom .8MB  = 55.2MB
    float*    h         = (float*)(ws);
    float*    out_accum = (float*)(ws + 25600000);
    float*    a_s       = (float*)(ws + 51200000);
    float*    a_d       = (float*)(ws + 52000000);
    unsigned* emax_enc  = (unsigned*)(ws + 52800000);
    float*    emaxf     = (float*)(ws + 53600000);
    float*    denom     = (float*)(ws + 54400000);

    k1_gemm<<<N_NODES / 8, 256, 0, stream>>>(x, W, att_src, att_dst, h, a_s, a_d, emax_enc);
    k2_edge_max<<<N_EDGES / 256, 256, 0, stream>>>(ei, a_s, a_d, emax_enc);
    k3_node_init<<<N_NODES * HC / 256, 256, 0, stream>>>(h, a_s, a_d, emax_enc, emaxf, denom, out_accum);
    k4_edge_msg<<<N_EDGES * 64 / 256, 256, 0, stream>>>(ei, a_s, a_d, emaxf, h, denom, out_accum);
    k5_final<<<N_NODES * 64 / 256, 256, 0, stream>>>(out_accum, denom, bias, gamma, beta, out);
}

// Round 2
// 386.788 us; speedup vs baseline: 1.9102x; 1.9102x over previous
//
#include <hip/hip_runtime.h>
#include <hip/hip_bf16.h>
#include <cstdint>
#include <cstddef>

#define N_NODES 50000
#define N_EDGES 800000
#define IN_DIM 256
#define HC 128          // HEADS*OUT_DIM
#define HEADS 4
#define NEG_SLOPE 0.2f
#define LN_EPS 1e-5f

__device__ __forceinline__ float lrelu(float x) { return x > 0.f ? x : NEG_SLOPE * x; }

// K1: h = x@W (8 rows/block), fused per-(node,head) a_s/a_d dot products
__global__ __launch_bounds__(256) void k1_gemm(
    const float* __restrict__ x, const float* __restrict__ W,
    const float* __restrict__ att_src, const float* __restrict__ att_dst,
    float* __restrict__ h, float* __restrict__ a_s, float* __restrict__ a_d)
{
    __shared__ float xs[8][IN_DIM];
    const int tid = threadIdx.x;
    const int n0 = blockIdx.x * 8;

    const float4* xg = (const float4*)(x + (size_t)n0 * IN_DIM);
    float4* xs4 = (float4*)&xs[0][0];
    xs4[tid] = xg[tid];
    xs4[tid + 256] = xg[tid + 256];
    __syncthreads();

    const int c = tid & 127;   // output column 0..127
    const int rg = tid >> 7;   // row group: rows rg*4 .. rg*4+3
    float acc0 = 0.f, acc1 = 0.f, acc2 = 0.f, acc3 = 0.f;
    const float* r0 = xs[rg * 4 + 0];
    const float* r1 = xs[rg * 4 + 1];
    const float* r2 = xs[rg * 4 + 2];
    const float* r3 = xs[rg * 4 + 3];
#pragma unroll 4
    for (int k = 0; k < IN_DIM; ++k) {
        float w = W[k * HC + c];        // coalesced, L2-resident (128 KB)
        acc0 += r0[k] * w;
        acc1 += r1[k] * w;
        acc2 += r2[k] * w;
        acc3 += r3[k] * w;
    }
    size_t hb = (size_t)(n0 + rg * 4) * HC + c;
    h[hb + 0 * HC] = acc0;
    h[hb + 1 * HC] = acc1;
    h[hb + 2 * HC] = acc2;
    h[hb + 3 * HC] = acc3;

    // per-(row,head) dot with att vectors via 32-lane butterfly (head = c>>5)
    float avs = att_src[c], avd = att_dst[c];
    float s0 = acc0 * avs, s1 = acc1 * avs, s2 = acc2 * avs, s3 = acc3 * avs;
    float d0 = acc0 * avd, d1 = acc1 * avd, d2 = acc2 * avd, d3 = acc3 * avd;
#pragma unroll
    for (int off = 16; off; off >>= 1) {
        s0 += __shfl_xor(s0, off, 32); d0 += __shfl_xor(d0, off, 32);
        s1 += __shfl_xor(s1, off, 32); d1 += __shfl_xor(d1, off, 32);
        s2 += __shfl_xor(s2, off, 32); d2 += __shfl_xor(d2, off, 32);
        s3 += __shfl_xor(s3, off, 32); d3 += __shfl_xor(d3, off, 32);
    }
    if ((c & 31) == 0) {
        int head = c >> 5;
        int n = n0 + rg * 4;
        float ss[4] = {s0, s1, s2, s3};
        float dd[4] = {d0, d1, d2, d3};
#pragma unroll
        for (int i = 0; i < 4; ++i) {
            int idx = (n + i) * HEADS + head;
            a_s[idx] = ss[i];
            a_d[idx] = dd[i];
        }
    }
}

// K2a: zero the histogram (ws is poisoned 0xAA every call)
__global__ __launch_bounds__(256) void k_zero(int* __restrict__ counts) {
    int i = blockIdx.x * 256 + threadIdx.x;
    if (i < N_NODES) counts[i] = 0;
}

// K2b: histogram of dst
__global__ __launch_bounds__(256) void k_hist(const int* __restrict__ ei,
                                              int* __restrict__ counts) {
    int e = blockIdx.x * 256 + threadIdx.x;
    if (e < N_EDGES) atomicAdd(&counts[ei[N_EDGES + e]], 1);
}

// K3a/b/c: hierarchical exclusive scan of counts -> starts (and cursor copy)
__global__ __launch_bounds__(256) void k_scan1(const int* __restrict__ counts,
                                               int* __restrict__ starts,
                                               int* __restrict__ bsum) {
    __shared__ int s[256];
    int i = blockIdx.x * 256 + threadIdx.x;
    int v = (i < N_NODES) ? counts[i] : 0;
    s[threadIdx.x] = v; __syncthreads();
#pragma unroll
    for (int off = 1; off < 256; off <<= 1) {
        int t = (threadIdx.x >= off) ? s[threadIdx.x - off] : 0;
        __syncthreads();
        s[threadIdx.x] += t;
        __syncthreads();
    }
    if (i < N_NODES) starts[i] = s[threadIdx.x] - v;   // exclusive within block
    if (threadIdx.x == 255) bsum[blockIdx.x] = s[255];
}
__global__ __launch_bounds__(256) void k_scan2(int* __restrict__ bsum, int nb) {
    __shared__ int s[256];
    int v = (threadIdx.x < nb) ? bsum[threadIdx.x] : 0;
    s[threadIdx.x] = v; __syncthreads();
#pragma unroll
    for (int off = 1; off < 256; off <<= 1) {
        int t = (threadIdx.x >= off) ? s[threadIdx.x - off] : 0;
        __syncthreads();
        s[threadIdx.x] += t;
        __syncthreads();
    }
    if (threadIdx.x < nb) bsum[threadIdx.x] = s[threadIdx.x] - v; // exclusive
}
__global__ __launch_bounds__(256) void k_scan3(int* __restrict__ starts,
                                               const int* __restrict__ bsum,
                                               int* __restrict__ cursor) {
    int i = blockIdx.x * 256 + threadIdx.x;
    if (i < N_NODES) {
        int s2 = starts[i] + bsum[blockIdx.x];
        starts[i] = s2;
        cursor[i] = s2;
    }
}

// K4: scatter src indices into dst-sorted order
__global__ __launch_bounds__(256) void k_scatter(const int* __restrict__ ei,
                                                 int* __restrict__ cursor,
                                                 int* __restrict__ ssrc) {
    int e = blockIdx.x * 256 + threadIdx.x;
    if (e >= N_EDGES) return;
    int src = ei[e], dst = ei[N_EDGES + e];
    int p = atomicAdd(&cursor[dst], 1);
    ssrc[p] = src;
}

// K5: one wave per node — segment softmax (max + exp-sum), h[src] gather-accumulate,
// normalize, +bias, LayerNorm (shuffle reduce), ELU, store. No atomics.
__global__ __launch_bounds__(256) void k_gather(
    const int* __restrict__ starts, const int* __restrict__ counts,
    const int* __restrict__ ssrc, const float* __restrict__ a_s,
    const float* __restrict__ a_d, const float* __restrict__ h,
    const float* __restrict__ bias, const float* __restrict__ gamma,
    const float* __restrict__ beta, float* __restrict__ out)
{
    int gid = blockIdx.x * 256 + threadIdx.x;
    int n = gid >> 6, lane = gid & 63;
    if (n >= N_NODES) return;

    const int beg = starts[n], deg = counts[n];
    const int hiHalf = (lane >> 5) & 1;          // head A = hiHalf, head B = 2+hiHalf

    float4 ad4 = *(const float4*)(a_d + (size_t)n * HEADS);
    float4 asS = *(const float4*)(a_s + (size_t)n * HEADS);
    const float adA = hiHalf ? ad4.y : ad4.x;
    const float adB = hiHalf ? ad4.w : ad4.z;
    const float lSelfA = lrelu((hiHalf ? asS.y : asS.x) + adA);
    const float lSelfB = lrelu((hiHalf ? asS.w : asS.z) + adB);

    // ---- pass A: per-head max over segment (self-loop seeds) ----
    float mA = lSelfA, mB = lSelfB;
    for (int base = 0; base < deg; base += 64) {
        int nc = min(64, deg - base);
        int sv = (lane < nc) ? ssrc[beg + base + lane] : 0;
        for (int j = 0; j < nc; ++j) {
            int src = __shfl(sv, j, 64);
            float4 as = *(const float4*)(a_s + (size_t)src * HEADS); // broadcast
            mA = fmaxf(mA, lrelu((hiHalf ? as.y : as.x) + adA));
            mB = fmaxf(mB, lrelu((hiHalf ? as.w : as.z) + adB));
        }
    }

    // ---- pass B: exp-weights, denom, register accumulate of h[src] ----
    const float wSelfA = __expf(lSelfA - mA);
    const float wSelfB = __expf(lSelfB - mB);
    float denA = wSelfA, denB = wSelfB;
    size_t hn = (size_t)n * HC;
    float accA = h[hn + lane] * wSelfA;
    float accB = h[hn + 64 + lane] * wSelfB;
    for (int base = 0; base < deg; base += 64) {
        int nc = min(64, deg - base);
        int sv = (lane < nc) ? ssrc[beg + base + lane] : 0;
        for (int j = 0; j < nc; ++j) {
            int src = __shfl(sv, j, 64);
            float4 as = *(const float4*)(a_s + (size_t)src * HEADS); // broadcast
            float wA = __expf(lrelu((hiHalf ? as.y : as.x) + adA) - mA);
            float wB = __expf(lrelu((hiHalf ? as.w : as.z) + adB) - mB);
            size_t sb = (size_t)src * HC;
            accA += h[sb + lane] * wA;        // 256B coalesced gather
            accB += h[sb + 64 + lane] * wB;   // 256B coalesced gather
            denA += wA;
            denB += wB;
        }
    }

    // ---- epilogue: normalize + bias + LayerNorm + ELU ----
    int c0 = lane, c1 = lane + 64;
    float v0 = accA / denA + bias[c0];
    float v1 = accB / denB + bias[c1];
    float s = v0 + v1;
#pragma unroll
    for (int off = 32; off; off >>= 1) s += __shfl_xor(s, off, 64);
    float mu = s * (1.f / 128.f);
    float d0 = v0 - mu, d1 = v1 - mu;
    float q = d0 * d0 + d1 * d1;
#pragma unroll
    for (int off = 32; off; off >>= 1) q += __shfl_xor(q, off, 64);
    float rs = rsqrtf(q * (1.f / 128.f) + LN_EPS);
    float o0 = d0 * rs * gamma[c0] + beta[c0];
    float o1 = d1 * rs * gamma[c1] + beta[c1];
    o0 = o0 > 0.f ? o0 : __expf(o0) - 1.f;
    o1 = o1 > 0.f ? o1 : __expf(o1) - 1.f;
    size_t ob = (size_t)n * HC;
    out[ob + c0] = o0;
    out[ob + c1] = o1;
}

extern "C" void kernel_launch(void* const* d_in, const int* in_sizes, int n_in,
                              void* d_out, int out_size, void* d_ws, size_t ws_size,
                              hipStream_t stream) {
    const float* x       = (const float*)d_in[0];
    const int*   ei      = (const int*)d_in[1];   // [2, E] int32: row0=src, row1=dst
    const float* W       = (const float*)d_in[2];
    const float* att_src = (const float*)d_in[3];
    const float* att_dst = (const float*)d_in[4];
    const float* bias    = (const float*)d_in[5];
    const float* gamma   = (const float*)d_in[6];
    const float* beta    = (const float*)d_in[7];
    float* out = (float*)d_out;

    char* ws = (char*)d_ws;
    // layout (16B-aligned): h 25.6MB | a_s .8MB | a_d .8MB | ssrc 3.2MB
    //                       | counts .2MB | starts .2MB | cursor .2MB | bsum 1KB
    float* h      = (float*)(ws);
    float* a_s    = (float*)(ws + 25600000);
    float* a_d    = (float*)(ws + 26400000);
    int*   ssrc   = (int*)  (ws + 27200000);
    int*   counts = (int*)  (ws + 30400000);
    int*   starts = (int*)  (ws + 30600000);
    int*   cursor = (int*)  (ws + 30800000);
    int*   bsum   = (int*)  (ws + 31000000);

    const int NB = (N_NODES + 255) / 256;   // 196 scan blocks (<=256)

    k1_gemm<<<N_NODES / 8, 256, 0, stream>>>(x, W, att_src, att_dst, h, a_s, a_d);
    k_zero<<<NB, 256, 0, stream>>>(counts);
    k_hist<<<(N_EDGES + 255) / 256, 256, 0, stream>>>(ei, counts);
    k_scan1<<<NB, 256, 0, stream>>>(counts, starts, bsum);
    k_scan2<<<1, 256, 0, stream>>>(bsum, NB);
    k_scan3<<<NB, 256, 0, stream>>>(starts, bsum, cursor);
    k_scatter<<<(N_EDGES + 255) / 256, 256, 0, stream>>>(ei, cursor, ssrc);
    k_gather<<<(N_NODES * 64 + 255) / 256, 256, 0, stream>>>(
        starts, counts, ssrc, a_s, a_d, h, bias, gamma, beta, out);
}